// Round 2
// baseline (1803.088 us; speedup 1.0000x reference)
//
#include <hip/hip_runtime.h>
#include <math.h>
#include <stdint.h>

#define N_TOK   8192      // B*S = 4*2048
#define DMODEL  1024
#define DCODEX  64
#define KCODES  8192

// ---------------------------------------------------------------------------
// cn2[k] = sum_d codex[k][d]^2
__global__ __launch_bounds__(256) void codenorm_kernel(const float* __restrict__ codex,
                                                       float* __restrict__ cn2) {
    int k = blockIdx.x * 256 + threadIdx.x;
    const float4* p = (const float4*)(codex + (size_t)k * DCODEX);
    float s = 0.f;
#pragma unroll
    for (int i = 0; i < 16; ++i) {
        float4 v = p[i];
        s += v.x * v.x + v.y * v.y + v.z * v.z + v.w * v.w;
    }
    cn2[k] = s;
}

// ---------------------------------------------------------------------------
// H = tanh(Z @ W1 + b1): 128x128 tile, 256 thr (16x16), 8x8/thread (4+4 split),
// double-buffered LDS, one barrier per K-tile of 16.
__global__ __launch_bounds__(256, 2) void gemm1_tanh_kernel(const float* __restrict__ Z,
                                                            const float* __restrict__ W1,
                                                            const float* __restrict__ b1,
                                                            float* __restrict__ H) {
    __shared__ float As[2][16][132];   // As[buf][k][m] (A transposed)
    __shared__ float Bs[2][16][132];   // Bs[buf][k][n]
    const int tid = threadIdx.x;
    const int row0 = blockIdx.x * 128;
    const int col0 = blockIdx.y * 128;
    const int ty = tid >> 4, tx = tid & 15;

    float acc[8][8];
#pragma unroll
    for (int i = 0; i < 8; ++i)
#pragma unroll
        for (int j = 0; j < 8; ++j) acc[i][j] = 0.f;

    float4 pa[2], pb[2];
    // prologue: load tile 0
#pragma unroll
    for (int t = 0; t < 2; ++t) {
        int q = tid + t * 256;
        pa[t] = *(const float4*)(Z + (size_t)(row0 + (q >> 2)) * DMODEL + ((q & 3) * 4));
        pb[t] = *(const float4*)(W1 + (size_t)(q >> 5) * DMODEL + col0 + (q & 31) * 4);
    }
#pragma unroll
    for (int t = 0; t < 2; ++t) {
        int q = tid + t * 256;
        int r = q >> 2, kc = (q & 3) * 4;
        As[0][kc + 0][r] = pa[t].x; As[0][kc + 1][r] = pa[t].y;
        As[0][kc + 2][r] = pa[t].z; As[0][kc + 3][r] = pa[t].w;
        *(float4*)&Bs[0][q >> 5][(q & 31) * 4] = pb[t];
    }
    __syncthreads();

    int buf = 0;
    for (int k0 = 0; k0 < DMODEL; k0 += 16) {
        const bool more = (k0 + 16) < DMODEL;
        if (more) {
#pragma unroll
            for (int t = 0; t < 2; ++t) {
                int q = tid + t * 256;
                pa[t] = *(const float4*)(Z + (size_t)(row0 + (q >> 2)) * DMODEL + k0 + 16 + ((q & 3) * 4));
                pb[t] = *(const float4*)(W1 + (size_t)(k0 + 16 + (q >> 5)) * DMODEL + col0 + (q & 31) * 4);
            }
        }
#pragma unroll
        for (int k = 0; k < 16; ++k) {
            float a[8], b[8];
            *(float4*)&a[0] = *(const float4*)&As[buf][k][ty * 4];
            *(float4*)&a[4] = *(const float4*)&As[buf][k][64 + ty * 4];
            *(float4*)&b[0] = *(const float4*)&Bs[buf][k][tx * 4];
            *(float4*)&b[4] = *(const float4*)&Bs[buf][k][64 + tx * 4];
#pragma unroll
            for (int i = 0; i < 8; ++i)
#pragma unroll
                for (int j = 0; j < 8; ++j)
                    acc[i][j] = fmaf(a[i], b[j], acc[i][j]);
        }
        if (more) {
#pragma unroll
            for (int t = 0; t < 2; ++t) {
                int q = tid + t * 256;
                int r = q >> 2, kc = (q & 3) * 4;
                As[buf ^ 1][kc + 0][r] = pa[t].x; As[buf ^ 1][kc + 1][r] = pa[t].y;
                As[buf ^ 1][kc + 2][r] = pa[t].z; As[buf ^ 1][kc + 3][r] = pa[t].w;
                *(float4*)&Bs[buf ^ 1][q >> 5][(q & 31) * 4] = pb[t];
            }
        }
        __syncthreads();
        buf ^= 1;
    }

    float bv[8];
    *(float4*)&bv[0] = *(const float4*)(b1 + col0 + tx * 4);
    *(float4*)&bv[4] = *(const float4*)(b1 + col0 + 64 + tx * 4);
#pragma unroll
    for (int half = 0; half < 2; ++half)
#pragma unroll
        for (int i = 0; i < 4; ++i) {
            int r = row0 + half * 64 + ty * 4 + i;
            float o[8];
#pragma unroll
            for (int j = 0; j < 8; ++j) o[j] = tanhf(acc[half * 4 + i][j] + bv[j]);
            *(float4*)(H + (size_t)r * DMODEL + col0 + tx * 4)      = *(float4*)&o[0];
            *(float4*)(H + (size_t)r * DMODEL + col0 + 64 + tx * 4) = *(float4*)&o[4];
        }
}

// ---------------------------------------------------------------------------
// E = H @ W2 + b2 ; Ze = E / max(||E||_row, 1e-12)
// 32-token tile (256 blocks), K-tile 64, 256 thr (16x16), 2x4/thread
__global__ __launch_bounds__(256) void gemm2_norm_kernel(const float* __restrict__ H,
                                                         const float* __restrict__ W2,
                                                         const float* __restrict__ b2,
                                                         float* __restrict__ Ze) {
    __shared__ float As[64][36];   // As[k][m] transposed
    __shared__ float Bs[64][68];   // Bs[k][n]
    const int tid = threadIdx.x;
    const int row0 = blockIdx.x * 32;
    const int ty = tid >> 4, tx = tid & 15;

    float acc[2][4];
#pragma unroll
    for (int i = 0; i < 2; ++i)
#pragma unroll
        for (int j = 0; j < 4; ++j) acc[i][j] = 0.f;

    for (int k0 = 0; k0 < DMODEL; k0 += 64) {
        __syncthreads();   // WAR
#pragma unroll
        for (int t = 0; t < 2; ++t) {
            int q = tid + t * 256;
            int r = q >> 4, k4 = (q & 15) * 4;
            float4 v = *(const float4*)(H + (size_t)(row0 + r) * DMODEL + k0 + k4);
            As[k4 + 0][r] = v.x; As[k4 + 1][r] = v.y;
            As[k4 + 2][r] = v.z; As[k4 + 3][r] = v.w;
        }
#pragma unroll
        for (int t = 0; t < 4; ++t) {
            int q = tid + t * 256;
            int kk = q >> 4, c4 = (q & 15) * 4;
            *(float4*)&Bs[kk][c4] = *(const float4*)(W2 + (size_t)(k0 + kk) * DCODEX + c4);
        }
        __syncthreads();
#pragma unroll
        for (int k = 0; k < 64; ++k) {
            float2 a = *(const float2*)&As[k][ty * 2];
            float4 b = *(const float4*)&Bs[k][tx * 4];
            float bw[4] = {b.x, b.y, b.z, b.w};
#pragma unroll
            for (int j = 0; j < 4; ++j) {
                acc[0][j] = fmaf(a.x, bw[j], acc[0][j]);
                acc[1][j] = fmaf(a.y, bw[j], acc[1][j]);
            }
        }
    }
    float4 b2v4 = *(const float4*)(b2 + tx * 4);
    float b2v[4] = {b2v4.x, b2v4.y, b2v4.z, b2v4.w};
#pragma unroll
    for (int i = 0; i < 2; ++i) {
        float e[4];
#pragma unroll
        for (int j = 0; j < 4; ++j) e[j] = acc[i][j] + b2v[j];
        float ss = e[0] * e[0] + e[1] * e[1] + e[2] * e[2] + e[3] * e[3];
        ss += __shfl_xor(ss, 8, 64);
        ss += __shfl_xor(ss, 4, 64);
        ss += __shfl_xor(ss, 2, 64);
        ss += __shfl_xor(ss, 1, 64);
        float nrm = fmaxf(sqrtf(ss), 1e-12f);
        float o[4];
#pragma unroll
        for (int j = 0; j < 4; ++j) o[j] = e[j] / nrm;
        *(float4*)(Ze + (size_t)(row0 + ty * 2 + i) * DCODEX + tx * 4) = *(float4*)&o[0];
    }
}

// ---------------------------------------------------------------------------
// argmin_k (cn2[k] - 2 z.c) ; packed u64 atomicMin keys (ordered-float | idx)
__device__ __forceinline__ unsigned fenc(float f) {
    unsigned u = __float_as_uint(f);
    return (u & 0x80000000u) ? ~u : (u | 0x80000000u);
}

__global__ __launch_bounds__(256) void dist_argmin_kernel(const float* __restrict__ Ze,
                                                          const float* __restrict__ codex,
                                                          const float* __restrict__ cn2,
                                                          unsigned long long* __restrict__ gbest) {
    __shared__ float Zs[64][132];   // Zs[d][token]
    __shared__ float Cs[32][132];   // Cs[d][code], half-K at a time
    __shared__ unsigned long long red[128];
    const int tid = threadIdx.x;
    const int row0 = blockIdx.x * 128;
    const int strip0 = blockIdx.y * 1024;
    const int ty = tid >> 4, tx = tid & 15;

    if (tid < 128) red[tid] = 0xFFFFFFFFFFFFFFFFull;
#pragma unroll
    for (int t = 0; t < 8; ++t) {
        int q = tid + t * 256;
        int r = q >> 4, d4 = (q & 15) * 4;
        float4 v = *(const float4*)(Ze + (size_t)(row0 + r) * DCODEX + d4);
        Zs[d4 + 0][r] = v.x; Zs[d4 + 1][r] = v.y;
        Zs[d4 + 2][r] = v.z; Zs[d4 + 3][r] = v.w;
    }

    float bv[8];
    int bi[8];
#pragma unroll
    for (int i = 0; i < 8; ++i) { bv[i] = INFINITY; bi[i] = 0; }

    for (int c0 = 0; c0 < 1024; c0 += 128) {
        const int cbase = strip0 + c0;
        float cn[8];
        *(float4*)&cn[0] = *(const float4*)(cn2 + cbase + tx * 4);
        *(float4*)&cn[4] = *(const float4*)(cn2 + cbase + 64 + tx * 4);
        float s[8][8];
#pragma unroll
        for (int i = 0; i < 8; ++i)
#pragma unroll
            for (int j = 0; j < 8; ++j) s[i][j] = 0.f;

        for (int h = 0; h < 2; ++h) {
            __syncthreads();   // WAR on Cs (first pass also publishes Zs)
#pragma unroll
            for (int t = 0; t < 4; ++t) {
                int q = tid + t * 256;
                int c = q >> 3, d4 = (q & 7) * 4;
                float4 v = *(const float4*)(codex + (size_t)(cbase + c) * DCODEX + h * 32 + d4);
                Cs[d4 + 0][c] = v.x; Cs[d4 + 1][c] = v.y;
                Cs[d4 + 2][c] = v.z; Cs[d4 + 3][c] = v.w;
            }
            __syncthreads();
#pragma unroll
            for (int d = 0; d < 32; ++d) {
                float a[8], b[8];
                *(float4*)&a[0] = *(const float4*)&Zs[h * 32 + d][ty * 4];
                *(float4*)&a[4] = *(const float4*)&Zs[h * 32 + d][64 + ty * 4];
                *(float4*)&b[0] = *(const float4*)&Cs[d][tx * 4];
                *(float4*)&b[4] = *(const float4*)&Cs[d][64 + tx * 4];
#pragma unroll
                for (int i = 0; i < 8; ++i)
#pragma unroll
                    for (int j = 0; j < 8; ++j)
                        s[i][j] = fmaf(a[i], b[j], s[i][j]);
            }
        }
#pragma unroll
        for (int i = 0; i < 8; ++i)
#pragma unroll
            for (int j = 0; j < 8; ++j) {
                float dist = fmaf(-2.0f, s[i][j], cn[j]);
                int col = cbase + ((j < 4) ? (tx * 4 + j) : (64 + tx * 4 + j - 4));
                if (dist < bv[i]) { bv[i] = dist; bi[i] = col; }
            }
    }
#pragma unroll
    for (int i = 0; i < 8; ++i) {
        int li = (i < 4) ? (ty * 4 + i) : (64 + ty * 4 + i - 4);
        unsigned long long key =
            ((unsigned long long)fenc(bv[i]) << 32) | (unsigned)bi[i];
        atomicMin(&red[li], key);
    }
    __syncthreads();
    if (tid < 128) atomicMin(&gbest[row0 + tid], red[tid]);
}

// ---------------------------------------------------------------------------
__global__ __launch_bounds__(256) void scatter_onehot_kernel(const unsigned long long* __restrict__ gbest,
                                                             int* __restrict__ idxbuf,
                                                             float* __restrict__ probs) {
    int n = blockIdx.x * 256 + threadIdx.x;
    unsigned id = (unsigned)(gbest[n] & 0xFFFFFFFFull);
    idxbuf[n] = (int)id;
    probs[(size_t)n * KCODES + id] = 1.0f;
}

// ---------------------------------------------------------------------------
// STE + LayerNorm + commitment loss; writes normalized rows to Aln
// one wave per token, 4 tokens per block
__global__ __launch_bounds__(256) void ln_loss_kernel(const int* __restrict__ idxbuf,
                                                      const float* __restrict__ codex,
                                                      const float* __restrict__ Ze,
                                                      const float* __restrict__ ln_w,
                                                      const float* __restrict__ ln_b,
                                                      float* __restrict__ Aln,
                                                      float* __restrict__ loss) {
    const int tid = threadIdx.x;
    const int w = tid >> 6, l = tid & 63;
    const int row = blockIdx.x * 4 + w;
    int id = idxbuf[row];
    float zq = codex[(size_t)id * DCODEX + l];
    float ze = Ze[(size_t)row * DCODEX + l];
    float dlt = zq - ze;
    float val = ze + dlt;   // STE forward value (reference rounding)
    float s = val;
#pragma unroll
    for (int m = 32; m >= 1; m >>= 1) s += __shfl_xor(s, m, 64);
    float mu = s * 0.015625f;
    float c = val - mu;
    float v2 = c * c;
#pragma unroll
    for (int m = 32; m >= 1; m >>= 1) v2 += __shfl_xor(v2, m, 64);
    float var = v2 * 0.015625f;
    float y = c * (1.0f / sqrtf(var + 1e-5f)) * ln_w[l] + ln_b[l];
    Aln[(size_t)row * DCODEX + l] = y;
    float d2 = dlt * dlt;
#pragma unroll
    for (int m = 32; m >= 1; m >>= 1) d2 += __shfl_xor(d2, m, 64);
    if (l == 0) atomicAdd(loss, d2 * (1.0f / 524288.0f));  // BETA=1, /(N*64)
}

// ---------------------------------------------------------------------------
// Zq = Aln @ Wp + bp : 128x64 tile, grid (64,16), 8x4/thread, K=64 one-shot
__global__ __launch_bounds__(256) void gemm3_kernel(const float* __restrict__ Aln,
                                                    const float* __restrict__ Wp,
                                                    const float* __restrict__ bp,
                                                    float* __restrict__ Zq) {
    __shared__ float As[64][132];   // As[d][token]
    __shared__ float Bs[64][68];    // Bs[d][col]
    const int tid = threadIdx.x;
    const int row0 = blockIdx.x * 128;
    const int col0 = blockIdx.y * 64;
    const int ty = tid >> 4, tx = tid & 15;

#pragma unroll
    for (int t = 0; t < 8; ++t) {
        int q = tid + t * 256;
        int r = q >> 4, d4 = (q & 15) * 4;
        float4 v = *(const float4*)(Aln + (size_t)(row0 + r) * DCODEX + d4);
        As[d4 + 0][r] = v.x; As[d4 + 1][r] = v.y;
        As[d4 + 2][r] = v.z; As[d4 + 3][r] = v.w;
    }
#pragma unroll
    for (int t = 0; t < 4; ++t) {
        int q = tid + t * 256;
        int kk = q >> 4, c4 = (q & 15) * 4;
        *(float4*)&Bs[kk][c4] = *(const float4*)(Wp + (size_t)kk * DMODEL + col0 + c4);
    }
    __syncthreads();

    float acc[8][4];
#pragma unroll
    for (int i = 0; i < 8; ++i)
#pragma unroll
        for (int j = 0; j < 4; ++j) acc[i][j] = 0.f;
#pragma unroll
    for (int k = 0; k < 64; ++k) {
        float a[8];
        *(float4*)&a[0] = *(const float4*)&As[k][ty * 4];
        *(float4*)&a[4] = *(const float4*)&As[k][64 + ty * 4];
        float4 b = *(const float4*)&Bs[k][tx * 4];
        float bw[4] = {b.x, b.y, b.z, b.w};
#pragma unroll
        for (int i = 0; i < 8; ++i)
#pragma unroll
            for (int j = 0; j < 4; ++j)
                acc[i][j] = fmaf(a[i], bw[j], acc[i][j]);
    }
    float4 bp4 = *(const float4*)(bp + col0 + tx * 4);
    float bb[4] = {bp4.x, bp4.y, bp4.z, bp4.w};
#pragma unroll
    for (int half = 0; half < 2; ++half)
#pragma unroll
        for (int i = 0; i < 4; ++i) {
            int r = row0 + half * 64 + ty * 4 + i;
            float o[4];
#pragma unroll
            for (int j = 0; j < 4; ++j) o[j] = acc[half * 4 + i][j] + bb[j];
            *(float4*)(Zq + (size_t)r * DMODEL + col0 + tx * 4) = *(float4*)&o[0];
        }
}

// ---------------------------------------------------------------------------
extern "C" void kernel_launch(void* const* d_in, const int* in_sizes, int n_in,
                              void* d_out, int out_size, void* d_ws, size_t ws_size,
                              hipStream_t stream) {
    const float* Z     = (const float*)d_in[0];
    const float* W1    = (const float*)d_in[1];
    const float* b1    = (const float*)d_in[2];
    const float* W2    = (const float*)d_in[3];
    const float* b2    = (const float*)d_in[4];
    const float* codex = (const float*)d_in[5];
    const float* ln_w  = (const float*)d_in[6];
    const float* ln_b  = (const float*)d_in[7];
    const float* Wp    = (const float*)d_in[8];
    const float* bp    = (const float*)d_in[9];

    float* out      = (float*)d_out;
    float* Zq_out   = out;                          // 8192*1024
    float* loss_out = out + (size_t)N_TOK * DMODEL; // 1
    float* probs    = loss_out + 1;                 // 8192*8192

    // workspace layout (~36 MB); Aln aliases H (H is dead after gemm2)
    char* ws = (char*)d_ws;
    float* H   = (float*)ws;                                   // 8192*1024
    float* Aln = H;                                            // 8192*64 (alias)
    float* Ze  = H + (size_t)N_TOK * DMODEL;                   // 8192*64
    float* cn2 = Ze + (size_t)N_TOK * DCODEX;                  // 8192
    unsigned long long* gbest = (unsigned long long*)(cn2 + KCODES);  // 8192
    int* idxbuf = (int*)(gbest + N_TOK);                       // 8192

    hipMemsetAsync(loss_out, 0, (size_t)(1 + (size_t)N_TOK * KCODES) * sizeof(float), stream);
    hipMemsetAsync(gbest, 0xFF, (size_t)N_TOK * sizeof(unsigned long long), stream);

    codenorm_kernel<<<KCODES / 256, 256, 0, stream>>>(codex, cn2);
    gemm1_tanh_kernel<<<dim3(N_TOK / 128, DMODEL / 128), 256, 0, stream>>>(Z, W1, b1, H);
    gemm2_norm_kernel<<<N_TOK / 32, 256, 0, stream>>>(H, W2, b2, Ze);
    dist_argmin_kernel<<<dim3(N_TOK / 128, KCODES / 1024), 256, 0, stream>>>(Ze, codex, cn2, gbest);
    scatter_onehot_kernel<<<N_TOK / 256, 256, 0, stream>>>(gbest, idxbuf, probs);
    ln_loss_kernel<<<N_TOK / 4, 256, 0, stream>>>(idxbuf, codex, Ze, ln_w, ln_b, Aln, loss_out);
    gemm3_kernel<<<dim3(N_TOK / 128, DMODEL / 64), 256, 0, stream>>>(Aln, Wp, bp, Zq_out);
}

// Round 3
// 815.340 us; speedup vs baseline: 2.2115x; 2.2115x over previous
//
#include <hip/hip_runtime.h>
#include <math.h>
#include <stdint.h>

#define N_TOK   8192      // B*S = 4*2048
#define DMODEL  1024
#define DCODEX  64
#define KCODES  8192

// ---------------------------------------------------------------------------
// cn2[k] = sum_d codex[k][d]^2
__global__ __launch_bounds__(256) void codenorm_kernel(const float* __restrict__ codex,
                                                       float* __restrict__ cn2) {
    int k = blockIdx.x * 256 + threadIdx.x;
    const float4* p = (const float4*)(codex + (size_t)k * DCODEX);
    float s = 0.f;
#pragma unroll
    for (int i = 0; i < 16; ++i) {
        float4 v = p[i];
        s += v.x * v.x + v.y * v.y + v.z * v.z + v.w * v.w;
    }
    cn2[k] = s;
}

// ---------------------------------------------------------------------------
// H = tanh(Z @ W1 + b1): 128x128 tile, grid (64,8)=512 blocks (2/CU),
// 256 thr (16x16), 8x8/thread with 4+4 split (conflict-free LDS reads),
// K-tile 32, single-buffered, no min-occupancy bound (avoid spills).
__global__ __launch_bounds__(256) void gemm1_tanh_kernel(const float* __restrict__ Z,
                                                         const float* __restrict__ W1,
                                                         const float* __restrict__ b1,
                                                         float* __restrict__ H) {
    __shared__ float As[32][132];   // As[k][m] (A transposed)
    __shared__ float Bs[32][132];   // Bs[k][n]
    const int tid = threadIdx.x;
    const int row0 = blockIdx.x * 128;
    const int col0 = blockIdx.y * 128;
    const int ty = tid >> 4, tx = tid & 15;

    float acc[8][8];
#pragma unroll
    for (int i = 0; i < 8; ++i)
#pragma unroll
        for (int j = 0; j < 8; ++j) acc[i][j] = 0.f;

    for (int k0 = 0; k0 < DMODEL; k0 += 32) {
        __syncthreads();   // WAR on As/Bs
        // A tile: 128 rows x 32 k = 1024 float4, 4 per thread, store transposed
#pragma unroll
        for (int t = 0; t < 4; ++t) {
            int q = tid + t * 256;
            int r = q >> 3, kc = (q & 7) * 4;
            float4 v = *(const float4*)(Z + (size_t)(row0 + r) * DMODEL + k0 + kc);
            As[kc + 0][r] = v.x; As[kc + 1][r] = v.y;
            As[kc + 2][r] = v.z; As[kc + 3][r] = v.w;
        }
        // B tile: 32 k x 128 cols = 1024 float4, 4 per thread
#pragma unroll
        for (int t = 0; t < 4; ++t) {
            int q = tid + t * 256;
            int kk = q >> 5, c4 = (q & 31) * 4;
            *(float4*)&Bs[kk][c4] =
                *(const float4*)(W1 + (size_t)(k0 + kk) * DMODEL + col0 + c4);
        }
        __syncthreads();
#pragma unroll
        for (int k = 0; k < 32; ++k) {
            float a[8], b[8];
            *(float4*)&a[0] = *(const float4*)&As[k][ty * 4];
            *(float4*)&a[4] = *(const float4*)&As[k][64 + ty * 4];
            *(float4*)&b[0] = *(const float4*)&Bs[k][tx * 4];
            *(float4*)&b[4] = *(const float4*)&Bs[k][64 + tx * 4];
#pragma unroll
            for (int i = 0; i < 8; ++i)
#pragma unroll
                for (int j = 0; j < 8; ++j)
                    acc[i][j] = fmaf(a[i], b[j], acc[i][j]);
        }
    }

    float bv[8];
    *(float4*)&bv[0] = *(const float4*)(b1 + col0 + tx * 4);
    *(float4*)&bv[4] = *(const float4*)(b1 + col0 + 64 + tx * 4);
#pragma unroll
    for (int half = 0; half < 2; ++half)
#pragma unroll
        for (int i = 0; i < 4; ++i) {
            int r = row0 + half * 64 + ty * 4 + i;
            float o[8];
#pragma unroll
            for (int j = 0; j < 8; ++j) o[j] = tanhf(acc[half * 4 + i][j] + bv[j]);
            *(float4*)(H + (size_t)r * DMODEL + col0 + tx * 4)      = *(float4*)&o[0];
            *(float4*)(H + (size_t)r * DMODEL + col0 + 64 + tx * 4) = *(float4*)&o[4];
        }
}

// ---------------------------------------------------------------------------
// E = H @ W2 + b2 ; Ze = E / max(||E||_row, 1e-12)
// 32-token tile (256 blocks), K-tile 64, 256 thr (16x16), 2x4/thread
__global__ __launch_bounds__(256) void gemm2_norm_kernel(const float* __restrict__ H,
                                                         const float* __restrict__ W2,
                                                         const float* __restrict__ b2,
                                                         float* __restrict__ Ze) {
    __shared__ float As[64][36];   // As[k][m] transposed
    __shared__ float Bs[64][68];   // Bs[k][n]
    const int tid = threadIdx.x;
    const int row0 = blockIdx.x * 32;
    const int ty = tid >> 4, tx = tid & 15;

    float acc[2][4];
#pragma unroll
    for (int i = 0; i < 2; ++i)
#pragma unroll
        for (int j = 0; j < 4; ++j) acc[i][j] = 0.f;

    for (int k0 = 0; k0 < DMODEL; k0 += 64) {
        __syncthreads();   // WAR
#pragma unroll
        for (int t = 0; t < 2; ++t) {
            int q = tid + t * 256;
            int r = q >> 4, k4 = (q & 15) * 4;
            float4 v = *(const float4*)(H + (size_t)(row0 + r) * DMODEL + k0 + k4);
            As[k4 + 0][r] = v.x; As[k4 + 1][r] = v.y;
            As[k4 + 2][r] = v.z; As[k4 + 3][r] = v.w;
        }
#pragma unroll
        for (int t = 0; t < 4; ++t) {
            int q = tid + t * 256;
            int kk = q >> 4, c4 = (q & 15) * 4;
            *(float4*)&Bs[kk][c4] = *(const float4*)(W2 + (size_t)(k0 + kk) * DCODEX + c4);
        }
        __syncthreads();
#pragma unroll
        for (int k = 0; k < 64; ++k) {
            float2 a = *(const float2*)&As[k][ty * 2];
            float4 b = *(const float4*)&Bs[k][tx * 4];
            float bw[4] = {b.x, b.y, b.z, b.w};
#pragma unroll
            for (int j = 0; j < 4; ++j) {
                acc[0][j] = fmaf(a.x, bw[j], acc[0][j]);
                acc[1][j] = fmaf(a.y, bw[j], acc[1][j]);
            }
        }
    }
    float4 b2v4 = *(const float4*)(b2 + tx * 4);
    float b2v[4] = {b2v4.x, b2v4.y, b2v4.z, b2v4.w};
#pragma unroll
    for (int i = 0; i < 2; ++i) {
        float e[4];
#pragma unroll
        for (int j = 0; j < 4; ++j) e[j] = acc[i][j] + b2v[j];
        float ss = e[0] * e[0] + e[1] * e[1] + e[2] * e[2] + e[3] * e[3];
        ss += __shfl_xor(ss, 8, 64);
        ss += __shfl_xor(ss, 4, 64);
        ss += __shfl_xor(ss, 2, 64);
        ss += __shfl_xor(ss, 1, 64);
        float nrm = fmaxf(sqrtf(ss), 1e-12f);
        float o[4];
#pragma unroll
        for (int j = 0; j < 4; ++j) o[j] = e[j] / nrm;
        *(float4*)(Ze + (size_t)(row0 + ty * 2 + i) * DCODEX + tx * 4) = *(float4*)&o[0];
    }
}

// ---------------------------------------------------------------------------
// argmin_k (cn2[k] - 2 z.c) ; packed u64 atomicMin keys (ordered-float | idx)
__device__ __forceinline__ unsigned fenc(float f) {
    unsigned u = __float_as_uint(f);
    return (u & 0x80000000u) ? ~u : (u | 0x80000000u);
}

__global__ __launch_bounds__(256) void dist_argmin_kernel(const float* __restrict__ Ze,
                                                          const float* __restrict__ codex,
                                                          const float* __restrict__ cn2,
                                                          unsigned long long* __restrict__ gbest) {
    __shared__ float Zs[64][132];   // Zs[d][token]
    __shared__ float Cs[32][132];   // Cs[d][code], half-K at a time
    __shared__ unsigned long long red[128];
    const int tid = threadIdx.x;
    const int row0 = blockIdx.x * 128;
    const int strip0 = blockIdx.y * 1024;
    const int ty = tid >> 4, tx = tid & 15;

    if (tid < 128) red[tid] = 0xFFFFFFFFFFFFFFFFull;
#pragma unroll
    for (int t = 0; t < 8; ++t) {
        int q = tid + t * 256;
        int r = q >> 4, d4 = (q & 15) * 4;
        float4 v = *(const float4*)(Ze + (size_t)(row0 + r) * DCODEX + d4);
        Zs[d4 + 0][r] = v.x; Zs[d4 + 1][r] = v.y;
        Zs[d4 + 2][r] = v.z; Zs[d4 + 3][r] = v.w;
    }

    float bv[8];
    int bi[8];
#pragma unroll
    for (int i = 0; i < 8; ++i) { bv[i] = INFINITY; bi[i] = 0; }

    for (int c0 = 0; c0 < 1024; c0 += 128) {
        const int cbase = strip0 + c0;
        float cn[8];
        *(float4*)&cn[0] = *(const float4*)(cn2 + cbase + tx * 4);
        *(float4*)&cn[4] = *(const float4*)(cn2 + cbase + 64 + tx * 4);
        float s[8][8];
#pragma unroll
        for (int i = 0; i < 8; ++i)
#pragma unroll
            for (int j = 0; j < 8; ++j) s[i][j] = 0.f;

        for (int h = 0; h < 2; ++h) {
            __syncthreads();   // WAR on Cs (first pass also publishes Zs)
#pragma unroll
            for (int t = 0; t < 4; ++t) {
                int q = tid + t * 256;
                int c = q >> 3, d4 = (q & 7) * 4;
                float4 v = *(const float4*)(codex + (size_t)(cbase + c) * DCODEX + h * 32 + d4);
                Cs[d4 + 0][c] = v.x; Cs[d4 + 1][c] = v.y;
                Cs[d4 + 2][c] = v.z; Cs[d4 + 3][c] = v.w;
            }
            __syncthreads();
#pragma unroll
            for (int d = 0; d < 32; ++d) {
                float a[8], b[8];
                *(float4*)&a[0] = *(const float4*)&Zs[h * 32 + d][ty * 4];
                *(float4*)&a[4] = *(const float4*)&Zs[h * 32 + d][64 + ty * 4];
                *(float4*)&b[0] = *(const float4*)&Cs[d][tx * 4];
                *(float4*)&b[4] = *(const float4*)&Cs[d][64 + tx * 4];
#pragma unroll
                for (int i = 0; i < 8; ++i)
#pragma unroll
                    for (int j = 0; j < 8; ++j)
                        s[i][j] = fmaf(a[i], b[j], s[i][j]);
            }
        }
#pragma unroll
        for (int i = 0; i < 8; ++i)
#pragma unroll
            for (int j = 0; j < 8; ++j) {
                float dist = fmaf(-2.0f, s[i][j], cn[j]);
                int col = cbase + ((j < 4) ? (tx * 4 + j) : (64 + tx * 4 + j - 4));
                if (dist < bv[i]) { bv[i] = dist; bi[i] = col; }
            }
    }
#pragma unroll
    for (int i = 0; i < 8; ++i) {
        int li = (i < 4) ? (ty * 4 + i) : (64 + ty * 4 + i - 4);
        unsigned long long key =
            ((unsigned long long)fenc(bv[i]) << 32) | (unsigned)bi[i];
        atomicMin(&red[li], key);
    }
    __syncthreads();
    if (tid < 128) atomicMin(&gbest[row0 + tid], red[tid]);
}

// ---------------------------------------------------------------------------
__global__ __launch_bounds__(256) void scatter_onehot_kernel(const unsigned long long* __restrict__ gbest,
                                                             int* __restrict__ idxbuf,
                                                             float* __restrict__ probs) {
    int n = blockIdx.x * 256 + threadIdx.x;
    unsigned id = (unsigned)(gbest[n] & 0xFFFFFFFFull);
    idxbuf[n] = (int)id;
    probs[(size_t)n * KCODES + id] = 1.0f;
}

// ---------------------------------------------------------------------------
// STE + LayerNorm + commitment loss; writes normalized rows to Aln
// one wave per token, 4 tokens per block
__global__ __launch_bounds__(256) void ln_loss_kernel(const int* __restrict__ idxbuf,
                                                      const float* __restrict__ codex,
                                                      const float* __restrict__ Ze,
                                                      const float* __restrict__ ln_w,
                                                      const float* __restrict__ ln_b,
                                                      float* __restrict__ Aln,
                                                      float* __restrict__ loss) {
    const int tid = threadIdx.x;
    const int w = tid >> 6, l = tid & 63;
    const int row = blockIdx.x * 4 + w;
    int id = idxbuf[row];
    float zq = codex[(size_t)id * DCODEX + l];
    float ze = Ze[(size_t)row * DCODEX + l];
    float dlt = zq - ze;
    float val = ze + dlt;   // STE forward value (reference rounding)
    float s = val;
#pragma unroll
    for (int m = 32; m >= 1; m >>= 1) s += __shfl_xor(s, m, 64);
    float mu = s * 0.015625f;
    float c = val - mu;
    float v2 = c * c;
#pragma unroll
    for (int m = 32; m >= 1; m >>= 1) v2 += __shfl_xor(v2, m, 64);
    float var = v2 * 0.015625f;
    float y = c * (1.0f / sqrtf(var + 1e-5f)) * ln_w[l] + ln_b[l];
    Aln[(size_t)row * DCODEX + l] = y;
    float d2 = dlt * dlt;
#pragma unroll
    for (int m = 32; m >= 1; m >>= 1) d2 += __shfl_xor(d2, m, 64);
    if (l == 0) atomicAdd(loss, d2 * (1.0f / 524288.0f));  // BETA=1, /(N*64)
}

// ---------------------------------------------------------------------------
// Zq = Aln @ Wp + bp : 128x64 tile, grid (64,16), 8x4/thread, K=64 one-shot
__global__ __launch_bounds__(256) void gemm3_kernel(const float* __restrict__ Aln,
                                                    const float* __restrict__ Wp,
                                                    const float* __restrict__ bp,
                                                    float* __restrict__ Zq) {
    __shared__ float As[64][132];   // As[d][token]
    __shared__ float Bs[64][68];    // Bs[d][col]
    const int tid = threadIdx.x;
    const int row0 = blockIdx.x * 128;
    const int col0 = blockIdx.y * 64;
    const int ty = tid >> 4, tx = tid & 15;

#pragma unroll
    for (int t = 0; t < 8; ++t) {
        int q = tid + t * 256;
        int r = q >> 4, d4 = (q & 15) * 4;
        float4 v = *(const float4*)(Aln + (size_t)(row0 + r) * DCODEX + d4);
        As[d4 + 0][r] = v.x; As[d4 + 1][r] = v.y;
        As[d4 + 2][r] = v.z; As[d4 + 3][r] = v.w;
    }
#pragma unroll
    for (int t = 0; t < 4; ++t) {
        int q = tid + t * 256;
        int kk = q >> 4, c4 = (q & 15) * 4;
        *(float4*)&Bs[kk][c4] = *(const float4*)(Wp + (size_t)kk * DMODEL + col0 + c4);
    }
    __syncthreads();

    float acc[8][4];
#pragma unroll
    for (int i = 0; i < 8; ++i)
#pragma unroll
        for (int j = 0; j < 4; ++j) acc[i][j] = 0.f;
#pragma unroll
    for (int k = 0; k < 64; ++k) {
        float a[8];
        *(float4*)&a[0] = *(const float4*)&As[k][ty * 4];
        *(float4*)&a[4] = *(const float4*)&As[k][64 + ty * 4];
        float4 b = *(const float4*)&Bs[k][tx * 4];
        float bw[4] = {b.x, b.y, b.z, b.w};
#pragma unroll
        for (int i = 0; i < 8; ++i)
#pragma unroll
            for (int j = 0; j < 4; ++j)
                acc[i][j] = fmaf(a[i], bw[j], acc[i][j]);
    }
    float4 bp4 = *(const float4*)(bp + col0 + tx * 4);
    float bb[4] = {bp4.x, bp4.y, bp4.z, bp4.w};
#pragma unroll
    for (int half = 0; half < 2; ++half)
#pragma unroll
        for (int i = 0; i < 4; ++i) {
            int r = row0 + half * 64 + ty * 4 + i;
            float o[4];
#pragma unroll
            for (int j = 0; j < 4; ++j) o[j] = acc[half * 4 + i][j] + bb[j];
            *(float4*)(Zq + (size_t)r * DMODEL + col0 + tx * 4) = *(float4*)&o[0];
        }
}

// ---------------------------------------------------------------------------
extern "C" void kernel_launch(void* const* d_in, const int* in_sizes, int n_in,
                              void* d_out, int out_size, void* d_ws, size_t ws_size,
                              hipStream_t stream) {
    const float* Z     = (const float*)d_in[0];
    const float* W1    = (const float*)d_in[1];
    const float* b1    = (const float*)d_in[2];
    const float* W2    = (const float*)d_in[3];
    const float* b2    = (const float*)d_in[4];
    const float* codex = (const float*)d_in[5];
    const float* ln_w  = (const float*)d_in[6];
    const float* ln_b  = (const float*)d_in[7];
    const float* Wp    = (const float*)d_in[8];
    const float* bp    = (const float*)d_in[9];

    float* out      = (float*)d_out;
    float* Zq_out   = out;                          // 8192*1024
    float* loss_out = out + (size_t)N_TOK * DMODEL; // 1
    float* probs    = loss_out + 1;                 // 8192*8192

    // workspace layout (~36 MB); Aln aliases H (H is dead after gemm2)
    char* ws = (char*)d_ws;
    float* H   = (float*)ws;                                   // 8192*1024
    float* Aln = H;                                            // 8192*64 (alias)
    float* Ze  = H + (size_t)N_TOK * DMODEL;                   // 8192*64
    float* cn2 = Ze + (size_t)N_TOK * DCODEX;                  // 8192
    unsigned long long* gbest = (unsigned long long*)(cn2 + KCODES);  // 8192
    int* idxbuf = (int*)(gbest + N_TOK);                       // 8192

    hipMemsetAsync(loss_out, 0, (size_t)(1 + (size_t)N_TOK * KCODES) * sizeof(float), stream);
    hipMemsetAsync(gbest, 0xFF, (size_t)N_TOK * sizeof(unsigned long long), stream);

    codenorm_kernel<<<KCODES / 256, 256, 0, stream>>>(codex, cn2);
    gemm1_tanh_kernel<<<dim3(N_TOK / 128, DMODEL / 128), 256, 0, stream>>>(Z, W1, b1, H);
    gemm2_norm_kernel<<<N_TOK / 32, 256, 0, stream>>>(H, W2, b2, Ze);
    dist_argmin_kernel<<<dim3(N_TOK / 128, KCODES / 1024), 256, 0, stream>>>(Ze, codex, cn2, gbest);
    scatter_onehot_kernel<<<N_TOK / 256, 256, 0, stream>>>(gbest, idxbuf, probs);
    ln_loss_kernel<<<N_TOK / 4, 256, 0, stream>>>(idxbuf, codex, Ze, ln_w, ln_b, Aln, loss_out);
    gemm3_kernel<<<dim3(N_TOK / 128, DMODEL / 64), 256, 0, stream>>>(Aln, Wp, bp, Zq_out);
}

// Round 4
// 731.504 us; speedup vs baseline: 2.4649x; 1.1146x over previous
//
#include <hip/hip_runtime.h>
#include <math.h>
#include <stdint.h>

#define N_TOK   8192      // B*S = 4*2048
#define DMODEL  1024
#define DCODEX  64
#define KCODES  8192

typedef short short8 __attribute__((ext_vector_type(8)));
typedef float f32x16 __attribute__((ext_vector_type(16)));

union Frag { short8 s; uint2 u[2]; };

// fp32 -> bf16 RNE, and back
__device__ __forceinline__ unsigned short f2bf(float f) {
    unsigned u = __float_as_uint(f);
    unsigned r = u + 0x7FFFu + ((u >> 16) & 1u);
    return (unsigned short)(r >> 16);
}
__device__ __forceinline__ float bf2f(unsigned short h) {
    return __uint_as_float(((unsigned)h) << 16);
}

// ---------------------------------------------------------------------------
// cn2[k] = sum_d codex[k][d]^2
__global__ __launch_bounds__(256) void codenorm_kernel(const float* __restrict__ codex,
                                                       float* __restrict__ cn2) {
    int k = blockIdx.x * 256 + threadIdx.x;
    const float4* p = (const float4*)(codex + (size_t)k * DCODEX);
    float s = 0.f;
#pragma unroll
    for (int i = 0; i < 16; ++i) {
        float4 v = p[i];
        s += v.x * v.x + v.y * v.y + v.z * v.z + v.w * v.w;
    }
    cn2[k] = s;
}

// ---------------------------------------------------------------------------
// Split W1 (k x n, fp32) into 3 transposed bf16 planes W1t_l[n][k] (hi/mid/lo).
// 32x32 tiles via LDS transpose.
__global__ __launch_bounds__(256) void split_w1_kernel(const float* __restrict__ W1,
                                                       unsigned short* __restrict__ t0,
                                                       unsigned short* __restrict__ t1,
                                                       unsigned short* __restrict__ t2) {
    __shared__ float tile[32][33];
    const int tid = threadIdx.x;
    const int k0 = blockIdx.x * 32;
    const int n0 = blockIdx.y * 32;
    {
        int i = tid >> 3, j4 = (tid & 7) * 4;
        float4 v = *(const float4*)(W1 + (size_t)(k0 + i) * DMODEL + n0 + j4);
        tile[i][j4 + 0] = v.x; tile[i][j4 + 1] = v.y;
        tile[i][j4 + 2] = v.z; tile[i][j4 + 3] = v.w;
    }
    __syncthreads();
    int n = tid >> 3, kq = (tid & 7) * 4;
    ushort4 h0, h1, h2;
#pragma unroll
    for (int c = 0; c < 4; ++c) {
        float f = tile[kq + c][n];
        unsigned short a0 = f2bf(f);
        float r1 = f - bf2f(a0);
        unsigned short a1 = f2bf(r1);
        float r2 = r1 - bf2f(a1);
        unsigned short a2 = f2bf(r2);
        ((unsigned short*)&h0)[c] = a0;
        ((unsigned short*)&h1)[c] = a1;
        ((unsigned short*)&h2)[c] = a2;
    }
    size_t off = (size_t)(n0 + n) * DMODEL + k0 + kq;
    *(ushort4*)(t0 + off) = h0;
    *(ushort4*)(t1 + off) = h1;
    *(ushort4*)(t2 + off) = h2;
}

// ---------------------------------------------------------------------------
// H = tanh(Z @ W1 + b1) via bf16x6 MFMA (hi/mid/lo split, fp32-fidelity).
// 128x128 block tile, 4 waves in 2x2, 64x64 per wave (2x2 of 32x32x16).
// A (Z) split on the fly; B from pre-split transposed W1t planes.
__global__ __launch_bounds__(256) void gemm1_mfma_kernel(const float* __restrict__ Z,
                                                         const unsigned short* __restrict__ W1t0,
                                                         const unsigned short* __restrict__ W1t1,
                                                         const unsigned short* __restrict__ W1t2,
                                                         const float* __restrict__ b1,
                                                         float* __restrict__ H) {
    __shared__ unsigned short Ash[3][128][36];   // [level][m][k] pitch 36
    __shared__ unsigned short Bsh[3][128][36];   // [level][n][k] pitch 36
    const int tid = threadIdx.x;
    const int row0 = blockIdx.x * 128;
    const int col0 = blockIdx.y * 128;
    const int wave = tid >> 6;
    const int lane = tid & 63;
    const int lrow = lane & 31;
    const int lhalf = lane >> 5;
    const int wm = wave >> 1, wn = wave & 1;

    f32x16 acc[2][2];
#pragma unroll
    for (int i = 0; i < 2; ++i)
#pragma unroll
        for (int j = 0; j < 2; ++j)
#pragma unroll
            for (int r = 0; r < 16; ++r) acc[i][j][r] = 0.f;

    for (int k0 = 0; k0 < DMODEL; k0 += 32) {
        __syncthreads();   // WAR on Ash/Bsh
        // --- stage A: 128 x 32 fp32, split to 3 bf16 planes ---
#pragma unroll
        for (int t = 0; t < 4; ++t) {
            int q = tid + t * 256;
            int r = q >> 3, kc = (q & 7) * 4;
            float4 v = *(const float4*)(Z + (size_t)(row0 + r) * DMODEL + k0 + kc);
            float f[4] = {v.x, v.y, v.z, v.w};
            unsigned h0[4], h1[4], h2[4];
#pragma unroll
            for (int c = 0; c < 4; ++c) {
                unsigned short a0 = f2bf(f[c]);
                float r1 = f[c] - bf2f(a0);
                unsigned short a1 = f2bf(r1);
                float r2 = r1 - bf2f(a1);
                unsigned short a2 = f2bf(r2);
                h0[c] = a0; h1[c] = a1; h2[c] = a2;
            }
            uint2 p0 = make_uint2(h0[0] | (h0[1] << 16), h0[2] | (h0[3] << 16));
            uint2 p1 = make_uint2(h1[0] | (h1[1] << 16), h1[2] | (h1[3] << 16));
            uint2 p2 = make_uint2(h2[0] | (h2[1] << 16), h2[2] | (h2[3] << 16));
            *(uint2*)&Ash[0][r][kc] = p0;
            *(uint2*)&Ash[1][r][kc] = p1;
            *(uint2*)&Ash[2][r][kc] = p2;
        }
        // --- stage B: 3 levels x 128 n x 32 k bf16 from W1t planes ---
#pragma unroll
        for (int t = 0; t < 6; ++t) {
            int e = tid + t * 256;
            int l = e >> 9;
            int rem = e & 511;
            int n = rem >> 2, kq = (rem & 3) * 8;
            const unsigned short* src = (l == 0) ? W1t0 : (l == 1) ? W1t1 : W1t2;
            uint4 v = *(const uint4*)(src + (size_t)(col0 + n) * DMODEL + k0 + kq);
            *(uint2*)&Bsh[l][n][kq]     = make_uint2(v.x, v.y);
            *(uint2*)&Bsh[l][n][kq + 4] = make_uint2(v.z, v.w);
        }
        __syncthreads();
        // --- compute: 2 micro-steps of k16 ---
#pragma unroll
        for (int mk = 0; mk < 2; ++mk) {
            const int kb = mk * 16 + lhalf * 8;
            Frag ah[2], am[2], al[2], bh[2], bm[2], bl[2];
#pragma unroll
            for (int ti = 0; ti < 2; ++ti) {
                int rA = wm * 64 + ti * 32 + lrow;
                ah[ti].u[0] = *(const uint2*)&Ash[0][rA][kb];
                ah[ti].u[1] = *(const uint2*)&Ash[0][rA][kb + 4];
                am[ti].u[0] = *(const uint2*)&Ash[1][rA][kb];
                am[ti].u[1] = *(const uint2*)&Ash[1][rA][kb + 4];
                al[ti].u[0] = *(const uint2*)&Ash[2][rA][kb];
                al[ti].u[1] = *(const uint2*)&Ash[2][rA][kb + 4];
            }
#pragma unroll
            for (int tj = 0; tj < 2; ++tj) {
                int rB = wn * 64 + tj * 32 + lrow;
                bh[tj].u[0] = *(const uint2*)&Bsh[0][rB][kb];
                bh[tj].u[1] = *(const uint2*)&Bsh[0][rB][kb + 4];
                bm[tj].u[0] = *(const uint2*)&Bsh[1][rB][kb];
                bm[tj].u[1] = *(const uint2*)&Bsh[1][rB][kb + 4];
                bl[tj].u[0] = *(const uint2*)&Bsh[2][rB][kb];
                bl[tj].u[1] = *(const uint2*)&Bsh[2][rB][kb + 4];
            }
#pragma unroll
            for (int ti = 0; ti < 2; ++ti)
#pragma unroll
                for (int tj = 0; tj < 2; ++tj) {
                    acc[ti][tj] = __builtin_amdgcn_mfma_f32_32x32x16_bf16(ah[ti].s, bh[tj].s, acc[ti][tj], 0, 0, 0);
                    acc[ti][tj] = __builtin_amdgcn_mfma_f32_32x32x16_bf16(ah[ti].s, bm[tj].s, acc[ti][tj], 0, 0, 0);
                    acc[ti][tj] = __builtin_amdgcn_mfma_f32_32x32x16_bf16(am[ti].s, bh[tj].s, acc[ti][tj], 0, 0, 0);
                    acc[ti][tj] = __builtin_amdgcn_mfma_f32_32x32x16_bf16(am[ti].s, bm[tj].s, acc[ti][tj], 0, 0, 0);
                    acc[ti][tj] = __builtin_amdgcn_mfma_f32_32x32x16_bf16(ah[ti].s, bl[tj].s, acc[ti][tj], 0, 0, 0);
                    acc[ti][tj] = __builtin_amdgcn_mfma_f32_32x32x16_bf16(al[ti].s, bh[tj].s, acc[ti][tj], 0, 0, 0);
                }
        }
    }

    // epilogue: bias + tanh, scalar dword stores (coalesced per 32-lane row)
    float b1v[2];
#pragma unroll
    for (int tj = 0; tj < 2; ++tj) b1v[tj] = b1[col0 + wn * 64 + tj * 32 + lrow];
#pragma unroll
    for (int ti = 0; ti < 2; ++ti)
#pragma unroll
        for (int tj = 0; tj < 2; ++tj) {
            int col = col0 + wn * 64 + tj * 32 + lrow;
#pragma unroll
            for (int r = 0; r < 16; ++r) {
                int row = row0 + wm * 64 + ti * 32 + (r & 3) + 8 * (r >> 2) + 4 * lhalf;
                H[(size_t)row * DMODEL + col] = tanhf(acc[ti][tj][r] + b1v[tj]);
            }
        }
}

// ---------------------------------------------------------------------------
// E = H @ W2 + b2 ; Ze = E / max(||E||_row, 1e-12)
__global__ __launch_bounds__(256) void gemm2_norm_kernel(const float* __restrict__ H,
                                                         const float* __restrict__ W2,
                                                         const float* __restrict__ b2,
                                                         float* __restrict__ Ze) {
    __shared__ float As[64][36];   // As[k][m] transposed
    __shared__ float Bs[64][68];   // Bs[k][n]
    const int tid = threadIdx.x;
    const int row0 = blockIdx.x * 32;
    const int ty = tid >> 4, tx = tid & 15;

    float acc[2][4];
#pragma unroll
    for (int i = 0; i < 2; ++i)
#pragma unroll
        for (int j = 0; j < 4; ++j) acc[i][j] = 0.f;

    for (int k0 = 0; k0 < DMODEL; k0 += 64) {
        __syncthreads();   // WAR
#pragma unroll
        for (int t = 0; t < 2; ++t) {
            int q = tid + t * 256;
            int r = q >> 4, k4 = (q & 15) * 4;
            float4 v = *(const float4*)(H + (size_t)(row0 + r) * DMODEL + k0 + k4);
            As[k4 + 0][r] = v.x; As[k4 + 1][r] = v.y;
            As[k4 + 2][r] = v.z; As[k4 + 3][r] = v.w;
        }
#pragma unroll
        for (int t = 0; t < 4; ++t) {
            int q = tid + t * 256;
            int kk = q >> 4, c4 = (q & 15) * 4;
            *(float4*)&Bs[kk][c4] = *(const float4*)(W2 + (size_t)(k0 + kk) * DCODEX + c4);
        }
        __syncthreads();
#pragma unroll
        for (int k = 0; k < 64; ++k) {
            float2 a = *(const float2*)&As[k][ty * 2];
            float4 b = *(const float4*)&Bs[k][tx * 4];
            float bw[4] = {b.x, b.y, b.z, b.w};
#pragma unroll
            for (int j = 0; j < 4; ++j) {
                acc[0][j] = fmaf(a.x, bw[j], acc[0][j]);
                acc[1][j] = fmaf(a.y, bw[j], acc[1][j]);
            }
        }
    }
    float4 b2v4 = *(const float4*)(b2 + tx * 4);
    float b2v[4] = {b2v4.x, b2v4.y, b2v4.z, b2v4.w};
#pragma unroll
    for (int i = 0; i < 2; ++i) {
        float e[4];
#pragma unroll
        for (int j = 0; j < 4; ++j) e[j] = acc[i][j] + b2v[j];
        float ss = e[0] * e[0] + e[1] * e[1] + e[2] * e[2] + e[3] * e[3];
        ss += __shfl_xor(ss, 8, 64);
        ss += __shfl_xor(ss, 4, 64);
        ss += __shfl_xor(ss, 2, 64);
        ss += __shfl_xor(ss, 1, 64);
        float nrm = fmaxf(sqrtf(ss), 1e-12f);
        float o[4];
#pragma unroll
        for (int j = 0; j < 4; ++j) o[j] = e[j] / nrm;
        *(float4*)(Ze + (size_t)(row0 + ty * 2 + i) * DCODEX + tx * 4) = *(float4*)&o[0];
    }
}

// ---------------------------------------------------------------------------
// argmin_k (cn2[k] - 2 z.c) ; packed u64 atomicMin keys (ordered-float | idx)
__device__ __forceinline__ unsigned fenc(float f) {
    unsigned u = __float_as_uint(f);
    return (u & 0x80000000u) ? ~u : (u | 0x80000000u);
}

__global__ __launch_bounds__(256) void dist_argmin_kernel(const float* __restrict__ Ze,
                                                          const float* __restrict__ codex,
                                                          const float* __restrict__ cn2,
                                                          unsigned long long* __restrict__ gbest) {
    __shared__ float Zs[64][132];   // Zs[d][token]
    __shared__ float Cs[32][132];   // Cs[d][code], half-K at a time
    __shared__ unsigned long long red[128];
    const int tid = threadIdx.x;
    const int row0 = blockIdx.x * 128;
    const int strip0 = blockIdx.y * 1024;
    const int ty = tid >> 4, tx = tid & 15;

    if (tid < 128) red[tid] = 0xFFFFFFFFFFFFFFFFull;
#pragma unroll
    for (int t = 0; t < 8; ++t) {
        int q = tid + t * 256;
        int r = q >> 4, d4 = (q & 15) * 4;
        float4 v = *(const float4*)(Ze + (size_t)(row0 + r) * DCODEX + d4);
        Zs[d4 + 0][r] = v.x; Zs[d4 + 1][r] = v.y;
        Zs[d4 + 2][r] = v.z; Zs[d4 + 3][r] = v.w;
    }

    float bv[8];
    int bi[8];
#pragma unroll
    for (int i = 0; i < 8; ++i) { bv[i] = INFINITY; bi[i] = 0; }

    for (int c0 = 0; c0 < 1024; c0 += 128) {
        const int cbase = strip0 + c0;
        float cn[8];
        *(float4*)&cn[0] = *(const float4*)(cn2 + cbase + tx * 4);
        *(float4*)&cn[4] = *(const float4*)(cn2 + cbase + 64 + tx * 4);
        float s[8][8];
#pragma unroll
        for (int i = 0; i < 8; ++i)
#pragma unroll
            for (int j = 0; j < 8; ++j) s[i][j] = 0.f;

        for (int h = 0; h < 2; ++h) {
            __syncthreads();   // WAR on Cs (first pass also publishes Zs)
#pragma unroll
            for (int t = 0; t < 4; ++t) {
                int q = tid + t * 256;
                int c = q >> 3, d4 = (q & 7) * 4;
                float4 v = *(const float4*)(codex + (size_t)(cbase + c) * DCODEX + h * 32 + d4);
                Cs[d4 + 0][c] = v.x; Cs[d4 + 1][c] = v.y;
                Cs[d4 + 2][c] = v.z; Cs[d4 + 3][c] = v.w;
            }
            __syncthreads();
#pragma unroll
            for (int d = 0; d < 32; ++d) {
                float a[8], b[8];
                *(float4*)&a[0] = *(const float4*)&Zs[h * 32 + d][ty * 4];
                *(float4*)&a[4] = *(const float4*)&Zs[h * 32 + d][64 + ty * 4];
                *(float4*)&b[0] = *(const float4*)&Cs[d][tx * 4];
                *(float4*)&b[4] = *(const float4*)&Cs[d][64 + tx * 4];
#pragma unroll
                for (int i = 0; i < 8; ++i)
#pragma unroll
                    for (int j = 0; j < 8; ++j)
                        s[i][j] = fmaf(a[i], b[j], s[i][j]);
            }
        }
#pragma unroll
        for (int i = 0; i < 8; ++i)
#pragma unroll
            for (int j = 0; j < 8; ++j) {
                float dist = fmaf(-2.0f, s[i][j], cn[j]);
                int col = cbase + ((j < 4) ? (tx * 4 + j) : (64 + tx * 4 + j - 4));
                if (dist < bv[i]) { bv[i] = dist; bi[i] = col; }
            }
    }
#pragma unroll
    for (int i = 0; i < 8; ++i) {
        int li = (i < 4) ? (ty * 4 + i) : (64 + ty * 4 + i - 4);
        unsigned long long key =
            ((unsigned long long)fenc(bv[i]) << 32) | (unsigned)bi[i];
        atomicMin(&red[li], key);
    }
    __syncthreads();
    if (tid < 128) atomicMin(&gbest[row0 + tid], red[tid]);
}

// ---------------------------------------------------------------------------
// probs = one_hot(argmin) : fused zero-fill + scatter (268 MB single pass)
__global__ __launch_bounds__(256) void zero_scatter_kernel(const unsigned long long* __restrict__ gbest,
                                                           float* __restrict__ probs) {
    size_t g = (size_t)blockIdx.x * 256 + threadIdx.x;
    int row = (int)(g >> 11);
    int c4i = (int)(g & 2047);
    unsigned id = (unsigned)(gbest[row] & 0xFFFFFFFFull);
    float4 v = {0.f, 0.f, 0.f, 0.f};
    if ((id >> 2) == (unsigned)c4i) ((float*)&v)[id & 3] = 1.0f;
    *(float4*)(probs + ((size_t)row << 13) + ((size_t)c4i << 2)) = v;
}

// ---------------------------------------------------------------------------
// STE + LayerNorm + commitment loss; writes normalized rows to Aln
__global__ __launch_bounds__(256) void ln_loss_kernel(const unsigned long long* __restrict__ gbest,
                                                      const float* __restrict__ codex,
                                                      const float* __restrict__ Ze,
                                                      const float* __restrict__ ln_w,
                                                      const float* __restrict__ ln_b,
                                                      float* __restrict__ Aln,
                                                      float* __restrict__ loss) {
    const int tid = threadIdx.x;
    const int w = tid >> 6, l = tid & 63;
    const int row = blockIdx.x * 4 + w;
    int id = (int)(unsigned)(gbest[row] & 0xFFFFFFFFull);
    float zq = codex[(size_t)id * DCODEX + l];
    float ze = Ze[(size_t)row * DCODEX + l];
    float dlt = zq - ze;
    float val = ze + dlt;   // STE forward value (reference rounding)
    float s = val;
#pragma unroll
    for (int m = 32; m >= 1; m >>= 1) s += __shfl_xor(s, m, 64);
    float mu = s * 0.015625f;
    float c = val - mu;
    float v2 = c * c;
#pragma unroll
    for (int m = 32; m >= 1; m >>= 1) v2 += __shfl_xor(v2, m, 64);
    float var = v2 * 0.015625f;
    float y = c * (1.0f / sqrtf(var + 1e-5f)) * ln_w[l] + ln_b[l];
    Aln[(size_t)row * DCODEX + l] = y;
    float d2 = dlt * dlt;
#pragma unroll
    for (int m = 32; m >= 1; m >>= 1) d2 += __shfl_xor(d2, m, 64);
    if (l == 0) atomicAdd(loss, d2 * (1.0f / 524288.0f));  // BETA=1, /(N*64)
}

// ---------------------------------------------------------------------------
// Zq = Aln @ Wp + bp : 128x64 tile, grid (64,16), 8x4/thread, K=64 one-shot
__global__ __launch_bounds__(256) void gemm3_kernel(const float* __restrict__ Aln,
                                                    const float* __restrict__ Wp,
                                                    const float* __restrict__ bp,
                                                    float* __restrict__ Zq) {
    __shared__ float As[64][132];   // As[d][token]
    __shared__ float Bs[64][68];    // Bs[d][col]
    const int tid = threadIdx.x;
    const int row0 = blockIdx.x * 128;
    const int col0 = blockIdx.y * 64;
    const int ty = tid >> 4, tx = tid & 15;

#pragma unroll
    for (int t = 0; t < 8; ++t) {
        int q = tid + t * 256;
        int r = q >> 4, d4 = (q & 15) * 4;
        float4 v = *(const float4*)(Aln + (size_t)(row0 + r) * DCODEX + d4);
        As[d4 + 0][r] = v.x; As[d4 + 1][r] = v.y;
        As[d4 + 2][r] = v.z; As[d4 + 3][r] = v.w;
    }
#pragma unroll
    for (int t = 0; t < 4; ++t) {
        int q = tid + t * 256;
        int kk = q >> 4, c4 = (q & 15) * 4;
        *(float4*)&Bs[kk][c4] = *(const float4*)(Wp + (size_t)kk * DMODEL + col0 + c4);
    }
    __syncthreads();

    float acc[8][4];
#pragma unroll
    for (int i = 0; i < 8; ++i)
#pragma unroll
        for (int j = 0; j < 4; ++j) acc[i][j] = 0.f;
#pragma unroll
    for (int k = 0; k < 64; ++k) {
        float a[8];
        *(float4*)&a[0] = *(const float4*)&As[k][ty * 4];
        *(float4*)&a[4] = *(const float4*)&As[k][64 + ty * 4];
        float4 b = *(const float4*)&Bs[k][tx * 4];
        float bw[4] = {b.x, b.y, b.z, b.w};
#pragma unroll
        for (int i = 0; i < 8; ++i)
#pragma unroll
            for (int j = 0; j < 4; ++j)
                acc[i][j] = fmaf(a[i], bw[j], acc[i][j]);
    }
    float4 bp4 = *(const float4*)(bp + col0 + tx * 4);
    float bb[4] = {bp4.x, bp4.y, bp4.z, bp4.w};
#pragma unroll
    for (int half = 0; half < 2; ++half)
#pragma unroll
        for (int i = 0; i < 4; ++i) {
            int r = row0 + half * 64 + ty * 4 + i;
            float o[4];
#pragma unroll
            for (int j = 0; j < 4; ++j) o[j] = acc[half * 4 + i][j] + bb[j];
            *(float4*)(Zq + (size_t)r * DMODEL + col0 + tx * 4) = *(float4*)&o[0];
        }
}

// ---------------------------------------------------------------------------
extern "C" void kernel_launch(void* const* d_in, const int* in_sizes, int n_in,
                              void* d_out, int out_size, void* d_ws, size_t ws_size,
                              hipStream_t stream) {
    const float* Z     = (const float*)d_in[0];
    const float* W1    = (const float*)d_in[1];
    const float* b1    = (const float*)d_in[2];
    const float* W2    = (const float*)d_in[3];
    const float* b2    = (const float*)d_in[4];
    const float* codex = (const float*)d_in[5];
    const float* ln_w  = (const float*)d_in[6];
    const float* ln_b  = (const float*)d_in[7];
    const float* Wp    = (const float*)d_in[8];
    const float* bp    = (const float*)d_in[9];

    float* out      = (float*)d_out;
    float* Zq_out   = out;                          // 8192*1024
    float* loss_out = out + (size_t)N_TOK * DMODEL; // 1
    float* probs    = loss_out + 1;                 // 8192*8192

    // workspace layout (~40 MB); Aln aliases H (H dead after gemm2)
    char* ws = (char*)d_ws;
    float* H   = (float*)ws;                                   // 8192*1024 fp32
    float* Aln = H;                                            // 8192*64 (alias)
    float* Ze  = H + (size_t)N_TOK * DMODEL;                   // 8192*64
    float* cn2 = Ze + (size_t)N_TOK * DCODEX;                  // 8192
    unsigned long long* gbest = (unsigned long long*)(cn2 + KCODES);   // 8192
    unsigned short* W1t0 = (unsigned short*)(gbest + N_TOK);   // 1024*1024 bf16
    unsigned short* W1t1 = W1t0 + (size_t)DMODEL * DMODEL;
    unsigned short* W1t2 = W1t1 + (size_t)DMODEL * DMODEL;

    hipMemsetAsync(loss_out, 0, sizeof(float), stream);
    hipMemsetAsync(gbest, 0xFF, (size_t)N_TOK * sizeof(unsigned long long), stream);

    codenorm_kernel<<<KCODES / 256, 256, 0, stream>>>(codex, cn2);
    split_w1_kernel<<<dim3(DMODEL / 32, DMODEL / 32), 256, 0, stream>>>(W1, W1t0, W1t1, W1t2);
    gemm1_mfma_kernel<<<dim3(N_TOK / 128, DMODEL / 128), 256, 0, stream>>>(Z, W1t0, W1t1, W1t2, b1, H);
    gemm2_norm_kernel<<<N_TOK / 32, 256, 0, stream>>>(H, W2, b2, Ze);
    dist_argmin_kernel<<<dim3(N_TOK / 128, KCODES / 1024), 256, 0, stream>>>(Ze, codex, cn2, gbest);
    zero_scatter_kernel<<<(int)(((size_t)N_TOK * KCODES / 4) / 256), 256, 0, stream>>>(gbest, probs);
    ln_loss_kernel<<<N_TOK / 4, 256, 0, stream>>>(gbest, codex, Ze, ln_w, ln_b, Aln, loss_out);
    gemm3_kernel<<<dim3(N_TOK / 128, DMODEL / 64), 256, 0, stream>>>(Aln, Wp, bp, Zq_out);
}